// Round 4
// baseline (641.516 us; speedup 1.0000x reference)
//
#include <hip/hip_runtime.h>
#include <hip/hip_bf16.h>

// GCN layer: N=100000, E=1600000, IN=256, OUT=32, fp32.
// R11 post-mortem: LDS-accumulate agg was right mechanism, wrong codegen —
// VGPR=8, zero MLP, 379us (compiler won't hoist gathers over LDS atomics).
// Also learned: sort_agg was ~91us (largest kernel).
// R12: (1) agg restructured into explicit phases: 8 shfl -> 8 independent
// gathers into regs -> 8 ds_adds; loads precede atomics in program order so
// no hoisting needed. Degree = one predicated per-lane LDS atomic per
// 32-edge batch. (2) S-side collapse: scale_out via direct global int
// atomics (E atomics into 400KB, L2-resident) + in-place rsqrt; removes
// partition_src + src_count, halves hist, offset now D-only 1 block.
// Pipeline: hist(D) -> offset(D) -> memset+src_degree -> cnt_to_scale ->
//           gemm -> partition_dst -> agg (fused rsqrt+bias+relu).

#define IN_F 256
#define OUT_F 32

#define G_ROWS 128
#define G_BK 16

// buckets / partition
#define BSHIFT 7
#define BNODES 128
#define NBK 1024
#define PB_EDGES 8192

// ---------------- fast path ----------------

__global__ __launch_bounds__(1024) void hist_kernel(
    const int* __restrict__ dst, unsigned short* __restrict__ mhistD, int E) {
  __shared__ int hD[NBK];
  int tid = threadIdx.x;
  hD[tid] = 0;
  __syncthreads();
  int e0 = blockIdx.x * PB_EDGES + tid * 8;
  if (e0 + 8 <= E) {
    int4 b0 = ((const int4*)(dst + e0))[0], b1 = ((const int4*)(dst + e0))[1];
    int dd[8] = {b0.x, b0.y, b0.z, b0.w, b1.x, b1.y, b1.z, b1.w};
#pragma unroll
    for (int j = 0; j < 8; ++j) atomicAdd(&hD[dd[j] >> BSHIFT], 1);
  } else {
    for (int j = 0; j < 8; ++j) {
      int e = e0 + j;
      if (e < E) atomicAdd(&hD[dst[e] >> BSHIFT], 1);
    }
  }
  __syncthreads();
  mhistD[blockIdx.x * NBK + tid] = (unsigned short)hD[tid];
}

// D-only: converts mhistD counts to within-bucket per-block exclusive
// prefixes and writes baseD. 1 block; 4-wide batches keep 4 loads in flight.
__global__ __launch_bounds__(1024) void offset_kernel(
    unsigned short* __restrict__ mhistD, int* __restrict__ baseD, int npb) {
  __shared__ int wsum[16];
  unsigned short* mh = mhistD;
  int* bb = baseD;
  int b = threadIdx.x;
  int run = 0;
  int blk = 0;
  for (; blk + 4 <= npb; blk += 4) {
    int i0 = blk * NBK + b;
    int c0 = mh[i0];
    int c1 = mh[i0 + NBK];
    int c2 = mh[i0 + 2 * NBK];
    int c3 = mh[i0 + 3 * NBK];
    mh[i0] = (unsigned short)run;
    mh[i0 + NBK] = (unsigned short)(run + c0);
    mh[i0 + 2 * NBK] = (unsigned short)(run + c0 + c1);
    mh[i0 + 3 * NBK] = (unsigned short)(run + c0 + c1 + c2);
    run += c0 + c1 + c2 + c3;
  }
  for (; blk < npb; ++blk) {
    int idx = blk * NBK + b;
    int c = mh[idx];
    mh[idx] = (unsigned short)run;
    run += c;
  }
  int v = run, x = run;
#pragma unroll
  for (int d = 1; d < 64; d <<= 1) {
    int y = __shfl_up(x, d, 64);
    if ((b & 63) >= d) x += y;
  }
  if ((b & 63) == 63) wsum[b >> 6] = x;
  __syncthreads();
  int off = 0;
#pragma unroll
  for (int w = 0; w < 16; ++w)
    if (w < (b >> 6)) off += wsum[w];
  bb[b] = off + x - v;
  if (b == NBK - 1) bb[NBK] = off + x;
}

// out-degree via direct global atomics (cnt is 400KB, L2-resident).
__global__ __launch_bounds__(256) void src_degree_kernel(
    const int* __restrict__ src, int* __restrict__ cnt, int E) {
  int i0 = (blockIdx.x * 256 + threadIdx.x) * 4;
  if (i0 + 4 <= E) {
    int4 s = *(const int4*)(src + i0);
    atomicAdd(cnt + s.x, 1);
    atomicAdd(cnt + s.y, 1);
    atomicAdd(cnt + s.z, 1);
    atomicAdd(cnt + s.w, 1);
  } else {
    for (int j = 0; j < 4; ++j)
      if (i0 + j < E) atomicAdd(cnt + src[i0 + j], 1);
  }
}

// in-place int count -> float rsqrt scale
__global__ __launch_bounds__(256) void cnt_to_scale_ip_kernel(
    int* __restrict__ cnt_scale, int N) {
  int i = blockIdx.x * 256 + threadIdx.x;
  if (i < N) {
    int c = cnt_scale[i];
    float s = (c < 1) ? 1.f : rsqrtf((float)c);
    ((float*)cnt_scale)[i] = s;
  }
}

// Stage one 128x16 feat tile into LDS via global_load_lds (16B DMA).
// LDS dest is lane-linear (chunk p = q*256+tid); the k-chunk swizzle
// (p&3)^(row&3) is applied on the GLOBAL source address so the read side
// (ds_read_b128 at chunk (r<<2)|(c^(r&3))) is <=2-way bank-aliased (free).
__device__ __forceinline__ void stage_tile(
    const float* __restrict__ feat, float* sf, int row0, int k0, int N,
    int tid) {
#pragma unroll
  for (int q = 0; q < 2; ++q) {
    int p = q * 256 + tid;
    int row = p >> 2;
    int c = (p & 3) ^ (row & 3);
    int g = row0 + row;
    if (g >= N) g = N - 1;
    const float* gp = feat + (size_t)g * IN_F + k0 + c * 4;
    __builtin_amdgcn_global_load_lds(
        (const __attribute__((address_space(1))) unsigned int*)gp,
        (__attribute__((address_space(3))) unsigned int*)(sf + p * 4),
        16, 0, 0);
  }
}

// h[n][o] = scale_out[n] * sum_k feat[n][k] * W[k][o]
__global__ __launch_bounds__(256, 3) void gemm_kernel(
    const float* __restrict__ feat, const float* __restrict__ W,
    const float* __restrict__ scale_out, float* __restrict__ h, int N) {
  __shared__ float sW[IN_F * OUT_F];          // [k][o], 32 KB
  __shared__ float sF[2][G_ROWS * G_BK];      // 2 x 8 KB
  __shared__ float sScale[G_ROWS];

  int tid = threadIdx.x;
  {
    const float4* W4 = (const float4*)W;
    float4* sW4 = (float4*)sW;
#pragma unroll
    for (int i = 0; i < 8; ++i) sW4[tid + i * 256] = W4[tid + i * 256];
  }
  int row0 = blockIdx.x * G_ROWS;
  if (tid < G_ROWS) {
    int gr = row0 + tid;
    sScale[tid] = (gr < N) ? scale_out[gr] : 0.f;
  }

  stage_tile(feat, &sF[0][0], row0, 0, N, tid);

  int tr = tid >> 3;          // 0..31
  int cg = (tid & 7) * 4;     // col group

  float acc[4][4];
#pragma unroll
  for (int i = 0; i < 4; ++i)
#pragma unroll
    for (int c = 0; c < 4; ++c) acc[i][c] = 0.f;

  __syncthreads();            // tile 0 landed (vmcnt drained), sW ready

  const int NT = IN_F / G_BK;  // 16 tiles
  for (int t = 0; t < NT; ++t) {
    if (t + 1 < NT)
      stage_tile(feat, &sF[(t + 1) & 1][0], row0, (t + 1) * G_BK, N, tid);

    const float* sf = &sF[t & 1][0];
    int kb = t * G_BK;
#pragma unroll
    for (int c = 0; c < 4; ++c) {
      float4 a[4];
#pragma unroll
      for (int i = 0; i < 4; ++i) {
        int r = tr + 32 * i;
        int chunk = (r << 2) | (c ^ (r & 3));
        a[i] = *(const float4*)(sf + chunk * 4);
      }
#pragma unroll
      for (int j = 0; j < 4; ++j) {
        float4 w = *(const float4*)(sW + (kb + c * 4 + j) * OUT_F + cg);
#pragma unroll
        for (int i = 0; i < 4; ++i) {
          float aj = (j == 0) ? a[i].x : (j == 1) ? a[i].y
                   : (j == 2) ? a[i].z : a[i].w;
          acc[i][0] = fmaf(aj, w.x, acc[i][0]);
          acc[i][1] = fmaf(aj, w.y, acc[i][1]);
          acc[i][2] = fmaf(aj, w.z, acc[i][2]);
          acc[i][3] = fmaf(aj, w.w, acc[i][3]);
        }
      }
    }
    __syncthreads();          // next tile landed; cur buffer free
  }

#pragma unroll
  for (int i = 0; i < 4; ++i) {
    int r = tr + 32 * i;
    int g = row0 + r;
    if (g < N) {
      float s = sScale[r];
      float4 o = {acc[i][0] * s, acc[i][1] * s, acc[i][2] * s, acc[i][3] * s};
      *(float4*)(h + (size_t)g * OUT_F + cg) = o;
    }
  }
}

__global__ __launch_bounds__(1024) void partition_dst_kernel(
    const int* __restrict__ src, const int* __restrict__ dst,
    const unsigned short* __restrict__ mbaseD, const int* __restrict__ baseD,
    unsigned* __restrict__ pairs, int E) {
  __shared__ unsigned sbuf[PB_EDGES];   // 32 KB
  __shared__ int hist[NBK];
  __shared__ int lbase[NBK + 1];
  __shared__ int gbase[NBK];
  __shared__ int wsum[16];

  int tid = threadIdx.x;
  hist[tid] = 0;
  __syncthreads();

  int e0 = blockIdx.x * PB_EDGES + tid * 8;
  int myb[8], myslot[8];
  unsigned mypk[8];
  if (e0 + 8 <= E) {
    int4 a0 = ((const int4*)(src + e0))[0], a1 = ((const int4*)(src + e0))[1];
    int4 b0 = ((const int4*)(dst + e0))[0], b1 = ((const int4*)(dst + e0))[1];
    int ss[8] = {a0.x, a0.y, a0.z, a0.w, a1.x, a1.y, a1.z, a1.w};
    int dd[8] = {b0.x, b0.y, b0.z, b0.w, b1.x, b1.y, b1.z, b1.w};
#pragma unroll
    for (int j = 0; j < 8; ++j) {
      int b = dd[j] >> BSHIFT;
      myb[j] = b;
      mypk[j] = (unsigned)ss[j] | ((unsigned)(dd[j] & (BNODES - 1)) << 17);
      myslot[j] = atomicAdd(&hist[b], 1);
    }
  } else {
#pragma unroll
    for (int j = 0; j < 8; ++j) {
      int e = e0 + j;
      if (e < E) {
        int s = src[e], d = dst[e];
        int b = d >> BSHIFT;
        myb[j] = b;
        mypk[j] = (unsigned)s | ((unsigned)(d & (BNODES - 1)) << 17);
        myslot[j] = atomicAdd(&hist[b], 1);
      } else {
        myb[j] = -1;
      }
    }
  }
  __syncthreads();

  {
    int v = hist[tid];
    int x = v;
#pragma unroll
    for (int d = 1; d < 64; d <<= 1) {
      int y = __shfl_up(x, d, 64);
      if ((tid & 63) >= d) x += y;
    }
    if ((tid & 63) == 63) wsum[tid >> 6] = x;
    __syncthreads();
    int off = 0;
#pragma unroll
    for (int w = 0; w < 16; ++w)
      if (w < (tid >> 6)) off += wsum[w];
    lbase[tid] = off + x - v;
    if (tid == NBK - 1) lbase[NBK] = off + x;
    gbase[tid] = baseD[tid] + (int)mbaseD[blockIdx.x * NBK + tid];
  }
  __syncthreads();

#pragma unroll
  for (int j = 0; j < 8; ++j)
    if (myb[j] >= 0) sbuf[lbase[myb[j]] + myslot[j]] = mypk[j];
  __syncthreads();

  int total = lbase[NBK];
  int idx = tid * 8;
  if (idx < total) {
    int lo = 0, hi = NBK;
    while (hi - lo > 1) {
      int mid = (lo + hi) >> 1;
      if (lbase[mid] <= idx) lo = mid; else hi = mid;
    }
    int b = lo;
#pragma unroll
    for (int j = 0; j < 8; ++j, ++idx) {
      if (idx >= total) break;
      while (idx >= lbase[b + 1]) ++b;
      pairs[gbase[b] + (idx - lbase[b])] = sbuf[idx];
    }
  }
}

// Per 128-node dst bucket: direct LDS f32 accumulation, phase-structured
// for MLP: 8 shfl -> 8 independent gathers into regs -> 8 ds_adds (loads
// precede atomics in program order; compiler emits staggered vmcnt).
// Degree: one predicated per-lane LDS atomic per 32-edge batch.
__global__ __launch_bounds__(256) void agg_kernel(
    const unsigned* __restrict__ pairs, const int* __restrict__ baseD,
    const float* __restrict__ h, const float* __restrict__ bias,
    float* __restrict__ out, int N) {
  __shared__ float sacc[BNODES * OUT_F];   // 16 KB
  __shared__ int sdeg[BNODES];

  int tid = threadIdx.x;
  int lane = tid & 31;
  int grp = tid >> 5;      // 0..7

  {
    float4* a4 = (float4*)sacc;
#pragma unroll
    for (int i = 0; i < 4; ++i) a4[tid + i * 256] = float4{0.f, 0.f, 0.f, 0.f};
    if (tid < BNODES) sdeg[tid] = 0;
  }
  __syncthreads();

  int b = blockIdx.x;
  int start = baseD[b], end = baseD[b + 1];

  for (int base = start + grp * 32; base < end; base += 256) {
    int m = min(32, end - base);
    unsigned pk = (lane < m) ? pairs[base + lane] : 0u;
    if (lane < m) atomicAdd(&sdeg[pk >> 17], 1);
    if (m == 32) {
#pragma unroll
      for (int it0 = 0; it0 < 32; it0 += 8) {
        unsigned p[8];
        float f[8];
#pragma unroll
        for (int j = 0; j < 8; ++j) p[j] = __shfl(pk, it0 + j, 32);
#pragma unroll
        for (int j = 0; j < 8; ++j)
          f[j] = h[(size_t)(p[j] & 0x1FFFF) * OUT_F + lane];
#pragma unroll
        for (int j = 0; j < 8; ++j)
          atomicAdd(&sacc[(p[j] >> 17) * OUT_F + lane], f[j]);
      }
    } else {
      for (int it = 0; it < m; ++it) {
        unsigned p = __shfl(pk, it, 32);
        float f = h[(size_t)(p & 0x1FFFF) * OUT_F + lane];
        atomicAdd(&sacc[(p >> 17) * OUT_F + lane], f);
      }
    }
  }
  __syncthreads();

  float bv = bias[lane];
  int node0 = b << BSHIFT;
#pragma unroll
  for (int t = 0; t < 16; ++t) {
    int n = grp * 16 + t;
    int node = node0 + n;
    if (node < N) {
      int d = sdeg[n];
      float sc = d > 0 ? rsqrtf((float)d) : 1.f;
      out[(size_t)node * OUT_F + lane] =
          fmaxf(fmaf(sacc[n * OUT_F + lane], sc, bv), 0.f);
    }
  }
}

// ---------------- fallback (float-atomic) path ----------------
__global__ __launch_bounds__(256) void degree_kernel(
    const int* __restrict__ src, const int* __restrict__ dst,
    int* __restrict__ cnt_out, int* __restrict__ cnt_in, int E) {
  int i = blockIdx.x * 256 + threadIdx.x;
  if (i < E) {
    atomicAdd(cnt_out + src[i], 1);
    atomicAdd(cnt_in + dst[i], 1);
  }
}

__global__ __launch_bounds__(256) void cnt_to_scale_kernel(
    const int* __restrict__ cnt, float* __restrict__ scale, int N) {
  int i = blockIdx.x * 256 + threadIdx.x;
  if (i < N) {
    int c = cnt[i];
    scale[i] = (c < 1) ? 1.f : rsqrtf((float)c);
  }
}

__global__ __launch_bounds__(256) void aggregate_kernel(
    const int* __restrict__ src, const int* __restrict__ dst,
    const float* __restrict__ h, float* __restrict__ out, int E) {
  int lane = threadIdx.x & 31;
  int e = (blockIdx.x * 256 + threadIdx.x) >> 5;
  if (e >= E) return;
  float v = h[(size_t)src[e] * OUT_F + lane];
  unsafeAtomicAdd(out + (size_t)dst[e] * OUT_F + lane, v);
}

__global__ __launch_bounds__(256) void finalize_kernel(
    float* __restrict__ out, const int* __restrict__ cnt_in,
    const float* __restrict__ bias, int N) {
  int idx = blockIdx.x * 256 + threadIdx.x;
  if (idx >= N * 8) return;
  int n = idx >> 3;
  int o = (idx & 7) * 4;
  float dg = (float)cnt_in[n];
  float s = dg < 1.f ? 1.f : rsqrtf(dg);
  float4 bv = *(const float4*)(bias + o);
  float4 v = ((const float4*)out)[idx];
  v.x = fmaxf(fmaf(v.x, s, bv.x), 0.f);
  v.y = fmaxf(fmaf(v.y, s, bv.y), 0.f);
  v.z = fmaxf(fmaf(v.z, s, bv.z), 0.f);
  v.w = fmaxf(fmaf(v.w, s, bv.w), 0.f);
  ((float4*)out)[idx] = v;
}

extern "C" void kernel_launch(void* const* d_in, const int* in_sizes, int n_in,
                              void* d_out, int out_size, void* d_ws, size_t ws_size,
                              hipStream_t stream) {
  const float* feat = (const float*)d_in[0];
  const int* src = (const int*)d_in[1];
  const int* dst = (const int*)d_in[2];
  const float* weight = (const float*)d_in[3];
  const float* bias = (const float*)d_in[4];
  float* out = (float*)d_out;

  int N = in_sizes[0] / IN_F;
  int E = in_sizes[1];
  int nb = (N + BNODES - 1) >> BSHIFT;
  int npb = (E + PB_EDGES - 1) / PB_EDGES;

  float* h = (float*)d_ws;                                   // N*32 f32
  unsigned* pairs = (unsigned*)(h + (size_t)N * OUT_F);      // E u32
  unsigned short* mhistS = (unsigned short*)(pairs + E);     // npb*NBK u16 (unused)
  unsigned short* mhistD = mhistS + (size_t)npb * NBK;       // npb*NBK u16
  int* baseS = (int*)(mhistD + (size_t)npb * NBK);           // NBK+1 (unused)
  int* baseD = baseS + NBK + 1;                              // NBK+1
  float* scale_out = (float*)(baseD + NBK + 1);              // N f32 (aliased int cnt)

  size_t need = ((size_t)N * OUT_F + (size_t)E + (size_t)N + 2 * (NBK + 1)) * 4 +
                (size_t)npb * NBK * 2 * 2;
  bool fast = (ws_size >= need) && (N <= (1 << 17)) && (nb <= NBK);

  if (fast) {
    hist_kernel<<<npb, 1024, 0, stream>>>(dst, mhistD, E);
    offset_kernel<<<1, 1024, 0, stream>>>(mhistD, baseD, npb);
    hipMemsetAsync(scale_out, 0, (size_t)N * sizeof(int), stream);
    src_degree_kernel<<<(E + 1023) / 1024, 256, 0, stream>>>(
        src, (int*)scale_out, E);
    cnt_to_scale_ip_kernel<<<(N + 255) / 256, 256, 0, stream>>>(
        (int*)scale_out, N);
    gemm_kernel<<<(N + G_ROWS - 1) / G_ROWS, 256, 0, stream>>>(
        feat, weight, scale_out, h, N);
    partition_dst_kernel<<<npb, 1024, 0, stream>>>(src, dst, mhistD, baseD, pairs, E);
    agg_kernel<<<nb, 256, 0, stream>>>(pairs, baseD, h, bias, out, N);
  } else {
    int* cnt_out = (int*)(h + (size_t)N * OUT_F);
    int* cnt_in = cnt_out + N;
    float* scl = (float*)(cnt_in + N);
    hipMemsetAsync(cnt_out, 0, (size_t)2 * N * sizeof(int), stream);
    hipMemsetAsync(out, 0, (size_t)N * OUT_F * sizeof(float), stream);
    degree_kernel<<<(E + 255) / 256, 256, 0, stream>>>(src, dst, cnt_out, cnt_in, E);
    cnt_to_scale_kernel<<<(N + 255) / 256, 256, 0, stream>>>(cnt_out, scl, N);
    gemm_kernel<<<(N + G_ROWS - 1) / G_ROWS, 256, 0, stream>>>(feat, weight, scl, h, N);
    aggregate_kernel<<<(E + 7) / 8, 256, 0, stream>>>(src, dst, h, out, E);
    finalize_kernel<<<(N * 8 + 255) / 256, 256, 0, stream>>>(out, cnt_in, bias, N);
  }
}

// Round 5
// 471.798 us; speedup vs baseline: 1.3597x; 1.3597x over previous
//
#include <hip/hip_runtime.h>
#include <hip/hip_bf16.h>

// GCN layer: N=100000, E=1600000, IN=256, OUT=32, fp32.
// R11/R12 post-mortem: ANY inner loop mixing gathers with (LDS or global)
// atomics gets serialized by the compiler (ds_add acts as a scheduling
// fence; VGPR 8..24, VALUBusy ~2.5%, agg 356-379us). R13: restructure so
// the hot loop is pure loads + VALU adds: full counting sort to per-node
// CSR (degree2 -> 3-level scan -> scatter), then csr_agg = one 32-lane
// group per node, batches of 8 predicated gathers into registers,
// register tree-sum, fused rsqrt+bias+relu. No atomics, no LDS in the hot
// loop. Deletes hist/offset/partition_dst radix machinery entirely.
// Pipeline: memset -> degree2 -> cnt_to_scale -> scan_l1/l2/l3 -> gemm ->
//           scatter -> csr_agg.

#define IN_F 256
#define OUT_F 32

#define G_ROWS 128
#define G_BK 16

// ---------------- fast path ----------------

// out-degree + in-degree via direct global atomics (cnt arrays 800KB,
// L2-resident).
__global__ __launch_bounds__(256) void degree2_kernel(
    const int* __restrict__ src, const int* __restrict__ dst,
    int* __restrict__ cnt_out, int* __restrict__ cnt_in, int E) {
  int i0 = (blockIdx.x * 256 + threadIdx.x) * 4;
  if (i0 + 4 <= E) {
    int4 s = *(const int4*)(src + i0);
    int4 d = *(const int4*)(dst + i0);
    atomicAdd(cnt_out + s.x, 1);
    atomicAdd(cnt_out + s.y, 1);
    atomicAdd(cnt_out + s.z, 1);
    atomicAdd(cnt_out + s.w, 1);
    atomicAdd(cnt_in + d.x, 1);
    atomicAdd(cnt_in + d.y, 1);
    atomicAdd(cnt_in + d.z, 1);
    atomicAdd(cnt_in + d.w, 1);
  } else {
    for (int j = 0; j < 4; ++j) {
      int e = i0 + j;
      if (e < E) {
        atomicAdd(cnt_out + src[e], 1);
        atomicAdd(cnt_in + dst[e], 1);
      }
    }
  }
}

// in-place int count -> float rsqrt scale
__global__ __launch_bounds__(256) void cnt_to_scale_ip_kernel(
    int* __restrict__ cnt_scale, int N) {
  int i = blockIdx.x * 256 + threadIdx.x;
  if (i < N) {
    int c = cnt_scale[i];
    float s = (c < 1) ? 1.f : rsqrtf((float)c);
    ((float*)cnt_scale)[i] = s;
  }
}

// Hierarchical exclusive scan of cnt_in -> rowptr.
// L1: per-1024-block exclusive scan, block totals to btot.
__global__ __launch_bounds__(1024) void scan_l1_kernel(
    const int* __restrict__ cnt, int* __restrict__ rowptr,
    int* __restrict__ btot, int N) {
  __shared__ int ws[16];
  int tid = threadIdx.x;
  int i = blockIdx.x * 1024 + tid;
  int v = (i < N) ? cnt[i] : 0;
  int x = v;
#pragma unroll
  for (int d = 1; d < 64; d <<= 1) {
    int y = __shfl_up(x, d, 64);
    if ((tid & 63) >= d) x += y;
  }
  if ((tid & 63) == 63) ws[tid >> 6] = x;
  __syncthreads();
  int off = 0;
#pragma unroll
  for (int w = 0; w < 16; ++w)
    if (w < (tid >> 6)) off += ws[w];
  if (i < N) rowptr[i] = off + x - v;
  if (tid == 1023) btot[blockIdx.x] = off + x;
}

// L2: single block exclusive scan of block totals (nb <= 1024).
__global__ __launch_bounds__(1024) void scan_l2_kernel(
    int* __restrict__ btot, int nb) {
  __shared__ int ws[16];
  int tid = threadIdx.x;
  int v = (tid < nb) ? btot[tid] : 0;
  int x = v;
#pragma unroll
  for (int d = 1; d < 64; d <<= 1) {
    int y = __shfl_up(x, d, 64);
    if ((tid & 63) >= d) x += y;
  }
  if ((tid & 63) == 63) ws[tid >> 6] = x;
  __syncthreads();
  int off = 0;
#pragma unroll
  for (int w = 0; w < 16; ++w)
    if (w < (tid >> 6)) off += ws[w];
  if (tid < nb) btot[tid] = off + x - v;
}

// L3: add block offsets; emit rowptr and the scatter working copy.
__global__ __launch_bounds__(256) void scan_l3_kernel(
    int* __restrict__ rowptr, int* __restrict__ rowptr_work,
    const int* __restrict__ btot, int N, int E) {
  int i = blockIdx.x * 256 + threadIdx.x;
  if (i < N) {
    int r = rowptr[i] + btot[i >> 10];
    rowptr[i] = r;
    rowptr_work[i] = r;
  }
  if (i == N) rowptr[N] = E;
}

// Scatter edges into CSR order: slot via atomic on rowptr_work.
__global__ __launch_bounds__(256) void scatter_kernel(
    const int* __restrict__ src, const int* __restrict__ dst,
    int* __restrict__ rowptr_work, int* __restrict__ pairs, int E) {
  int i0 = (blockIdx.x * 256 + threadIdx.x) * 4;
  if (i0 + 4 <= E) {
    int4 s = *(const int4*)(src + i0);
    int4 d = *(const int4*)(dst + i0);
    int s0 = atomicAdd(rowptr_work + d.x, 1);
    int s1 = atomicAdd(rowptr_work + d.y, 1);
    int s2 = atomicAdd(rowptr_work + d.z, 1);
    int s3 = atomicAdd(rowptr_work + d.w, 1);
    pairs[s0] = s.x;
    pairs[s1] = s.y;
    pairs[s2] = s.z;
    pairs[s3] = s.w;
  } else {
    for (int j = 0; j < 4; ++j) {
      int e = i0 + j;
      if (e < E) {
        int slot = atomicAdd(rowptr_work + dst[e], 1);
        pairs[slot] = src[e];
      }
    }
  }
}

// Stage one 128x16 feat tile into LDS via global_load_lds (16B DMA).
// LDS dest is lane-linear (chunk p = q*256+tid); the k-chunk swizzle
// (p&3)^(row&3) is applied on the GLOBAL source address so the read side
// (ds_read_b128 at chunk (r<<2)|(c^(r&3))) is <=2-way bank-aliased (free).
__device__ __forceinline__ void stage_tile(
    const float* __restrict__ feat, float* sf, int row0, int k0, int N,
    int tid) {
#pragma unroll
  for (int q = 0; q < 2; ++q) {
    int p = q * 256 + tid;
    int row = p >> 2;
    int c = (p & 3) ^ (row & 3);
    int g = row0 + row;
    if (g >= N) g = N - 1;
    const float* gp = feat + (size_t)g * IN_F + k0 + c * 4;
    __builtin_amdgcn_global_load_lds(
        (const __attribute__((address_space(1))) unsigned int*)gp,
        (__attribute__((address_space(3))) unsigned int*)(sf + p * 4),
        16, 0, 0);
  }
}

// h[n][o] = scale_out[n] * sum_k feat[n][k] * W[k][o]
__global__ __launch_bounds__(256, 3) void gemm_kernel(
    const float* __restrict__ feat, const float* __restrict__ W,
    const float* __restrict__ scale_out, float* __restrict__ h, int N) {
  __shared__ float sW[IN_F * OUT_F];          // [k][o], 32 KB
  __shared__ float sF[2][G_ROWS * G_BK];      // 2 x 8 KB
  __shared__ float sScale[G_ROWS];

  int tid = threadIdx.x;
  {
    const float4* W4 = (const float4*)W;
    float4* sW4 = (float4*)sW;
#pragma unroll
    for (int i = 0; i < 8; ++i) sW4[tid + i * 256] = W4[tid + i * 256];
  }
  int row0 = blockIdx.x * G_ROWS;
  if (tid < G_ROWS) {
    int gr = row0 + tid;
    sScale[tid] = (gr < N) ? scale_out[gr] : 0.f;
  }

  stage_tile(feat, &sF[0][0], row0, 0, N, tid);

  int tr = tid >> 3;          // 0..31
  int cg = (tid & 7) * 4;     // col group

  float acc[4][4];
#pragma unroll
  for (int i = 0; i < 4; ++i)
#pragma unroll
    for (int c = 0; c < 4; ++c) acc[i][c] = 0.f;

  __syncthreads();            // tile 0 landed (vmcnt drained), sW ready

  const int NT = IN_F / G_BK;  // 16 tiles
  for (int t = 0; t < NT; ++t) {
    if (t + 1 < NT)
      stage_tile(feat, &sF[(t + 1) & 1][0], row0, (t + 1) * G_BK, N, tid);

    const float* sf = &sF[t & 1][0];
    int kb = t * G_BK;
#pragma unroll
    for (int c = 0; c < 4; ++c) {
      float4 a[4];
#pragma unroll
      for (int i = 0; i < 4; ++i) {
        int r = tr + 32 * i;
        int chunk = (r << 2) | (c ^ (r & 3));
        a[i] = *(const float4*)(sf + chunk * 4);
      }
#pragma unroll
      for (int j = 0; j < 4; ++j) {
        float4 w = *(const float4*)(sW + (kb + c * 4 + j) * OUT_F + cg);
#pragma unroll
        for (int i = 0; i < 4; ++i) {
          float aj = (j == 0) ? a[i].x : (j == 1) ? a[i].y
                   : (j == 2) ? a[i].z : a[i].w;
          acc[i][0] = fmaf(aj, w.x, acc[i][0]);
          acc[i][1] = fmaf(aj, w.y, acc[i][1]);
          acc[i][2] = fmaf(aj, w.z, acc[i][2]);
          acc[i][3] = fmaf(aj, w.w, acc[i][3]);
        }
      }
    }
    __syncthreads();          // next tile landed; cur buffer free
  }

#pragma unroll
  for (int i = 0; i < 4; ++i) {
    int r = tr + 32 * i;
    int g = row0 + r;
    if (g < N) {
      float s = sScale[r];
      float4 o = {acc[i][0] * s, acc[i][1] * s, acc[i][2] * s, acc[i][3] * s};
      *(float4*)(h + (size_t)g * OUT_F + cg) = o;
    }
  }
}

// CSR SpMM: one 32-lane group per dst node. Edges contiguous in pairs.
// Batches of 8 predicated gathers into registers, register tree-sum.
// No atomics, no LDS — pure load->add, compiler pipelines it.
__global__ __launch_bounds__(256) void csr_agg_kernel(
    const int* __restrict__ rowptr, const int* __restrict__ pairs,
    const float* __restrict__ h, const float* __restrict__ bias,
    float* __restrict__ out, int N) {
  int tid = threadIdx.x;
  int lane = tid & 31;
  int n = (blockIdx.x * 256 + tid) >> 5;   // global group id = node
  if (n >= N) return;
  int s = rowptr[n], e = rowptr[n + 1];
  int deg = e - s;

  float acc = 0.f;
  if (deg > 0) {
    for (int j = s; j < e; j += 8) {
      float f[8];
#pragma unroll
      for (int q = 0; q < 8; ++q) {
        int idx = j + q;
        int sn = pairs[idx < e ? idx : e - 1];
        float v = h[(size_t)sn * OUT_F + lane];
        f[q] = (idx < e) ? v : 0.f;
      }
      acc += ((f[0] + f[1]) + (f[2] + f[3])) + ((f[4] + f[5]) + (f[6] + f[7]));
    }
  }
  float sc = deg > 0 ? rsqrtf((float)deg) : 1.f;
  out[(size_t)n * OUT_F + lane] = fmaxf(fmaf(acc, sc, bias[lane]), 0.f);
}

// ---------------- fallback (float-atomic) path ----------------
__global__ __launch_bounds__(256) void degree_kernel(
    const int* __restrict__ src, const int* __restrict__ dst,
    int* __restrict__ cnt_out, int* __restrict__ cnt_in, int E) {
  int i = blockIdx.x * 256 + threadIdx.x;
  if (i < E) {
    atomicAdd(cnt_out + src[i], 1);
    atomicAdd(cnt_in + dst[i], 1);
  }
}

__global__ __launch_bounds__(256) void cnt_to_scale_kernel(
    const int* __restrict__ cnt, float* __restrict__ scale, int N) {
  int i = blockIdx.x * 256 + threadIdx.x;
  if (i < N) {
    int c = cnt[i];
    scale[i] = (c < 1) ? 1.f : rsqrtf((float)c);
  }
}

__global__ __launch_bounds__(256) void aggregate_kernel(
    const int* __restrict__ src, const int* __restrict__ dst,
    const float* __restrict__ h, float* __restrict__ out, int E) {
  int lane = threadIdx.x & 31;
  int e = (blockIdx.x * 256 + threadIdx.x) >> 5;
  if (e >= E) return;
  float v = h[(size_t)src[e] * OUT_F + lane];
  unsafeAtomicAdd(out + (size_t)dst[e] * OUT_F + lane, v);
}

__global__ __launch_bounds__(256) void finalize_kernel(
    float* __restrict__ out, const int* __restrict__ cnt_in,
    const float* __restrict__ bias, int N) {
  int idx = blockIdx.x * 256 + threadIdx.x;
  if (idx >= N * 8) return;
  int n = idx >> 3;
  int o = (idx & 7) * 4;
  float dg = (float)cnt_in[n];
  float s = dg < 1.f ? 1.f : rsqrtf(dg);
  float4 bv = *(const float4*)(bias + o);
  float4 v = ((const float4*)out)[idx];
  v.x = fmaxf(fmaf(v.x, s, bv.x), 0.f);
  v.y = fmaxf(fmaf(v.y, s, bv.y), 0.f);
  v.z = fmaxf(fmaf(v.z, s, bv.z), 0.f);
  v.w = fmaxf(fmaf(v.w, s, bv.w), 0.f);
  ((float4*)out)[idx] = v;
}

extern "C" void kernel_launch(void* const* d_in, const int* in_sizes, int n_in,
                              void* d_out, int out_size, void* d_ws, size_t ws_size,
                              hipStream_t stream) {
  const float* feat = (const float*)d_in[0];
  const int* src = (const int*)d_in[1];
  const int* dst = (const int*)d_in[2];
  const float* weight = (const float*)d_in[3];
  const float* bias = (const float*)d_in[4];
  float* out = (float*)d_out;

  int N = in_sizes[0] / IN_F;
  int E = in_sizes[1];

  float* h = (float*)d_ws;                         // N*32 f32
  int* pairs = (int*)(h + (size_t)N * OUT_F);      // E i32 (CSR src indices)
  int* cnt_in = pairs + E;                         // N
  int* scale_cnt = cnt_in + N;                     // N (count -> scale in place)
  int* rowptr = scale_cnt + N;                     // N+1
  int* rowptr_work = rowptr + N + 1;               // N
  int* btot = rowptr_work + N;                     // up to 1024

  size_t need = ((size_t)N * OUT_F + (size_t)E + 4 * (size_t)N + 1 + 1024) * 4;
  int nblk_scan = (N + 1023) / 1024;
  bool fast = (ws_size >= need) && (N <= (1 << 17));

  if (fast) {
    // cnt_in and scale_cnt are adjacent -> single memset
    hipMemsetAsync(cnt_in, 0, (size_t)2 * N * sizeof(int), stream);
    degree2_kernel<<<(E + 1023) / 1024, 256, 0, stream>>>(
        src, dst, scale_cnt, cnt_in, E);
    cnt_to_scale_ip_kernel<<<(N + 255) / 256, 256, 0, stream>>>(scale_cnt, N);
    scan_l1_kernel<<<nblk_scan, 1024, 0, stream>>>(cnt_in, rowptr, btot, N);
    scan_l2_kernel<<<1, 1024, 0, stream>>>(btot, nblk_scan);
    scan_l3_kernel<<<(N + 1 + 255) / 256, 256, 0, stream>>>(
        rowptr, rowptr_work, btot, N, E);
    gemm_kernel<<<(N + G_ROWS - 1) / G_ROWS, 256, 0, stream>>>(
        feat, weight, (const float*)scale_cnt, h, N);
    scatter_kernel<<<(E + 1023) / 1024, 256, 0, stream>>>(
        src, dst, rowptr_work, pairs, E);
    csr_agg_kernel<<<(N + 7) / 8, 256, 0, stream>>>(
        rowptr, pairs, h, bias, out, N);
  } else {
    int* cnt_out = (int*)(h + (size_t)N * OUT_F);
    int* cnt_in2 = cnt_out + N;
    float* scl = (float*)(cnt_in2 + N);
    hipMemsetAsync(cnt_out, 0, (size_t)2 * N * sizeof(int), stream);
    hipMemsetAsync(out, 0, (size_t)N * OUT_F * sizeof(float), stream);
    degree_kernel<<<(E + 255) / 256, 256, 0, stream>>>(src, dst, cnt_out, cnt_in2, E);
    cnt_to_scale_kernel<<<(N + 255) / 256, 256, 0, stream>>>(cnt_out, scl, N);
    gemm_kernel<<<(N + G_ROWS - 1) / G_ROWS, 256, 0, stream>>>(feat, weight, scl, h, N);
    aggregate_kernel<<<(E + 7) / 8, 256, 0, stream>>>(src, dst, h, out, E);
    finalize_kernel<<<(N * 8 + 255) / 256, 256, 0, stream>>>(out, cnt_in2, bias, N);
  }
}